// Round 3
// baseline (668.711 us; speedup 1.0000x reference)
//
#include <hip/hip_runtime.h>

// ---------------- problem constants ----------------
#define T 4096          // tokens (2*2048)
#define Hdim 1024       // hidden
#define Idim 4096       // intermediate
#define NE 8            // experts
#define OUT0 4194304    // T*Hdim (out elems), logits follow at d_out+OUT0 (T*NE)
#define SPLITK 4        // gemm2 split-K factor (fp32 atomic combine, no partials)
#define BK 64           // GEMM K-tile (32 KB LDS total, 2 MFMA k-steps per barrier)

// padded slot capacity: sum ceil(cnt_e/128)*128 <= 8192 + 8*128 = 9216
#define SLOT_CAP 9216

// ---------------- ws layout (bytes) ----------------
#define W1B_OFF 0u                    // bf16 w1 [E][I][H]   67108864
#define W2B_OFF 67108864u             // bf16 w2 [E][H][I]   67108864
#define XB_OFF  134217728u            // bf16 x  [T][H]       8388608
#define HB_OFF  142606336u            // bf16 h  [SLOT_CAP][I] 75497472
#define META_OFF 218103808u
// meta (int index):
#define M_COUNTS 0      // [8]
#define M_CURS   8      // [8]
#define M_TEXP   32     // [8192] token-pair -> expert
#define M_TSLOT  8224   // [8192] token-pair -> slot (kept for debug/layout stability)
#define M_STOK   16416  // [9216] slot -> token (-1 = pad)
#define M_TWF    25632  // float[8192] token-pair weight (reinterpret)
#define M_SWF    33824  // float[9216] slot weight (0 for pads)

typedef short bf16x8 __attribute__((ext_vector_type(8)));
typedef float f32x4  __attribute__((ext_vector_type(4)));

__device__ __forceinline__ unsigned short f2bf(float f) {
    unsigned int b = __float_as_uint(f);
    b += 0x7fffu + ((b >> 16) & 1u);      // round-nearest-even
    return (unsigned short)(b >> 16);
}
__device__ __forceinline__ float bf2f(unsigned short s) {
    return __uint_as_float(((unsigned int)s) << 16);
}

// async global->LDS DMA, 16B/lane. LDS dest is wave-uniform base + lane*16
// (m104); layout is linear-in-lane with the XOR swizzle pre-applied to the
// GLOBAL source address (rule #21), so content matches the swizzled ds_read.
#define GLD(gsrc, ldst) \
    __builtin_amdgcn_global_load_lds( \
        (const __attribute__((address_space(1))) unsigned int*)(gsrc), \
        (__attribute__((address_space(3))) unsigned int*)(ldst), 16, 0, 0)

// one launch: converts both weight tensors fp32->bf16, zeroes meta
// (counts/curs, stok pads, swf), and zeroes out[0..T*H) for the atomic
// combine. All happen-before consumers via stream order.
__global__ void cvt_w_k(const float* __restrict__ w1, const float* __restrict__ w2,
                        unsigned short* __restrict__ w1b, unsigned short* __restrict__ w2b,
                        int n4each, int* __restrict__ meta, float* __restrict__ out) {
    int i = blockIdx.x * blockDim.x + threadIdx.x;
    if (i < 16) meta[M_COUNTS + i] = 0;          // counts + cursors
    if (i < SLOT_CAP) {
        meta[M_STOK + i] = -1;                   // slot_token pad marker
        ((float*)(meta + M_SWF))[i] = 0.f;       // pad weight = 0
    }
    if (i < T * Hdim / 4) ((float4*)out)[i] = make_float4(0.f, 0.f, 0.f, 0.f);
    const float4* src; ushort4* dst; int j;
    if (i < n4each) { src = (const float4*)w1; dst = (ushort4*)w1b; j = i; }
    else            { src = (const float4*)w2; dst = (ushort4*)w2b; j = i - n4each; }
    float4 v = src[j];
    ushort4 o;
    o.x = f2bf(v.x); o.y = f2bf(v.y); o.z = f2bf(v.z); o.w = f2bf(v.w);
    dst[j] = o;
}

// fp32-exact router: logits, top-2, softmax, counts; also emits xb (bf16 x).
__global__ void router_k(const float* __restrict__ x, const float* __restrict__ gw,
                         float* __restrict__ logits_out, int* __restrict__ texp,
                         float* __restrict__ twf, int* __restrict__ counts,
                         unsigned short* __restrict__ xb) {
    int wv = threadIdx.x >> 6, lane = threadIdx.x & 63;
    int t = blockIdx.x * 4 + wv;
    const float* xp = x + (size_t)t * Hdim;
    unsigned short* xbp = xb + (size_t)t * Hdim;
    float s[NE];
    #pragma unroll
    for (int e = 0; e < NE; e++) s[e] = 0.f;
    #pragma unroll
    for (int j = 0; j < 16; j++) {
        float xv = xp[lane + 64 * j];
        xbp[lane + 64 * j] = f2bf(xv);
        #pragma unroll
        for (int e = 0; e < NE; e++) s[e] += xv * gw[e * Hdim + lane + 64 * j];
    }
    #pragma unroll
    for (int e = 0; e < NE; e++) {
        #pragma unroll
        for (int off = 32; off > 0; off >>= 1) s[e] += __shfl_xor(s[e], off);
    }
    if (lane == 0) {
        #pragma unroll
        for (int e = 0; e < NE; e++) logits_out[t * NE + e] = s[e];
        int i0 = 0; float v0 = s[0];
        #pragma unroll
        for (int e = 1; e < NE; e++) if (s[e] > v0) { v0 = s[e]; i0 = e; }
        int i1 = -1; float v1 = -3.4e38f;
        #pragma unroll
        for (int e = 0; e < NE; e++) if (e != i0 && s[e] > v1) { v1 = s[e]; i1 = e; }
        float e1 = expf(v1 - v0);            // v1<=v0, stable
        float inv = 1.f / (1.f + e1);
        texp[2 * t] = i0; texp[2 * t + 1] = i1;
        twf[2 * t] = inv; twf[2 * t + 1] = e1 * inv;
        atomicAdd(&counts[i0], 1);
        atomicAdd(&counts[i1], 1);
    }
}

// padded prefix-sum over counts computed inline (deterministic, identical
// formula everywhere). Also scatters the per-pair routing weight to its slot
// (swf) so gemm2's epilogue can do the weighted combine directly.
__global__ void assign_k(const int* __restrict__ texp, const int* __restrict__ counts,
                         const float* __restrict__ twf, int* __restrict__ curs,
                         int* __restrict__ stok, int* __restrict__ tslot,
                         float* __restrict__ swf) {
    int p = blockIdx.x * blockDim.x + threadIdx.x;  // pair id < 8192
    int e = texp[p];
    int off = 0;
    #pragma unroll
    for (int q = 0; q < NE; q++) {
        int pc = (counts[q] + 127) & ~127;
        off += (q < e) ? pc : 0;
    }
    int slot = off + atomicAdd(&curs[e], 1);
    stok[slot] = p >> 1;
    swf[slot] = twf[p];
    tslot[p] = slot;
}

// ---------------- grouped GEMM1: h = gelu(x @ w1[e]^T), bf16 out ----------------
// m97-style: direct async global->LDS, XOR swizzle pre-applied to the per-lane
// GLOBAL address, linear LDS dest (wave-uniform base + lane*16). 3 blocks/CU;
// grid 2304 = exactly 3 occupancy rounds.
__global__ __launch_bounds__(256, 3) void gemm1_k(
    const unsigned short* __restrict__ xb, const unsigned short* __restrict__ w1b,
    const int* __restrict__ counts, const int* __restrict__ stok,
    unsigned short* __restrict__ hb) {
    __shared__ __align__(16) unsigned short As[128 * BK];
    __shared__ __align__(16) unsigned short Bs[128 * BK];
    const int rt = blockIdx.y, ct = blockIdx.x;
    const int row0 = rt * 128;
    int offs[NE + 1];
    offs[0] = 0;
    #pragma unroll
    for (int q = 0; q < NE; q++) offs[q + 1] = offs[q] + ((counts[q] + 127) & ~127);
    if (row0 >= offs[NE]) return;
    int e = 0;
    #pragma unroll
    for (int q = 1; q < NE; q++) if (offs[q] <= row0) e = q;

    const int tid = threadIdx.x;
    const int lane = tid & 63, wv = tid >> 6;
    const int srow = lane >> 3;                 // row within 8-row staging group
    const int schunk = (lane & 7) ^ srow;       // swizzled source k-chunk (8 bf16)

    const unsigned short* gA[4];
    const unsigned short* gB[4];
    unsigned short* lA[4];
    unsigned short* lB[4];
    #pragma unroll
    for (int g = 0; g < 4; g++) {
        int r = wv * 32 + g * 8 + srow;
        int t = stok[row0 + r]; if (t < 0) t = 0;
        gA[g] = xb + (size_t)t * Hdim + schunk * 8;
        gB[g] = w1b + ((size_t)e * Idim + ct * 128 + r) * Hdim + schunk * 8;
        lA[g] = As + (wv * 32 + g * 8) * BK;    // wave-uniform LDS base
        lB[g] = Bs + (wv * 32 + g * 8) * BK;
    }

    f32x4 acc[4][4] = {};
    const int mrow = (wv & 1) * 64, ncol = (wv >> 1) * 64;
    const int fr = lane & 15, qd = lane >> 4;

    const int NIT = Hdim / BK;
    for (int it = 0; it < NIT; it++) {
        #pragma unroll
        for (int g = 0; g < 4; g++) {
            GLD(gA[g] + it * BK, lA[g]);
            GLD(gB[g] + it * BK, lB[g]);
        }
        __syncthreads();                      // vmcnt(0) drain -> tile resident
        #pragma unroll
        for (int ko = 0; ko < 2; ko++) {
            bf16x8 af[4], bff[4];
            #pragma unroll
            for (int mi = 0; mi < 4; mi++)
                af[mi]  = *(const bf16x8*)&As[(mrow + mi * 16 + fr) * BK + ((((ko << 2) | qd) ^ (fr & 7)) << 3)];
            #pragma unroll
            for (int ni = 0; ni < 4; ni++)
                bff[ni] = *(const bf16x8*)&Bs[(ncol + ni * 16 + fr) * BK + ((((ko << 2) | qd) ^ (fr & 7)) << 3)];
            #pragma unroll
            for (int mi = 0; mi < 4; mi++)
                #pragma unroll
                for (int ni = 0; ni < 4; ni++)
                    acc[mi][ni] = __builtin_amdgcn_mfma_f32_16x16x32_bf16(af[mi], bff[ni], acc[mi][ni], 0, 0, 0);
        }
        __syncthreads();                      // waves done reading before overwrite
    }
    // epilogue: tanh-form gelu (sigmoid identity) -> bf16.
    #pragma unroll
    for (int mi = 0; mi < 4; mi++) {
        #pragma unroll
        for (int ni = 0; ni < 4; ni++) {
            #pragma unroll
            for (int r = 0; r < 4; r++) {
                int row = row0 + mrow + mi * 16 + qd * 4 + r;
                int col = ct * 128 + ncol + ni * 16 + fr;
                float v = acc[mi][ni][r];
                float u = v * (1.f + 0.044715f * v * v);
                float g = v / (1.f + __expf(-1.5957691216f * u));
                hb[(size_t)row * Idim + col] = f2bf(g);
            }
        }
    }
}

// ---------------- grouped GEMM2 (split-K=4, fused weighted combine) ----------------
// 1D grid 2304 (= exactly 3 occupancy rounds at 3 blocks/CU; the old SPLITK=2
// grid of 1152 left round 2 half-empty). XCD-territory decode: XCD k = id%8
// owns rt in [9k, 9k+9) for all (ct, kz). Epilogue scales by the slot's
// routing weight and atomicAdd's fp32 into out -- deletes the y-partial
// round-trip and the combine launch; pads contribute 0 via swf=0/stok=-1.
__global__ __launch_bounds__(256, 3) void gemm2_k(
    const unsigned short* __restrict__ hb, const unsigned short* __restrict__ w2b,
    const int* __restrict__ counts, const int* __restrict__ stok,
    const float* __restrict__ swf, float* __restrict__ out) {
    __shared__ __align__(16) unsigned short As[128 * BK];
    __shared__ __align__(16) unsigned short Bs[128 * BK];
    const int id = blockIdx.x;
    const int k8 = id & 7;                 // intended XCD
    const int j  = id >> 3;                // per-XCD sequence 0..287
    const int ct = j & 7;                  // B col tile (Hdim/128 = 8)
    const int j8 = j >> 3;                 // 0..35
    const int rtL = j8 % 9, kz = j8 / 9;   // kz in 0..3
    const int rt = k8 * 9 + rtL;
    const int row0 = rt * 128;
    int offs[NE + 1];
    offs[0] = 0;
    #pragma unroll
    for (int q = 0; q < NE; q++) offs[q + 1] = offs[q] + ((counts[q] + 127) & ~127);
    if (row0 >= offs[NE]) return;
    int e = 0;
    #pragma unroll
    for (int q = 1; q < NE; q++) if (offs[q] <= row0) e = q;

    const int tid = threadIdx.x;
    const int lane = tid & 63, wv = tid >> 6;
    const int srow = lane >> 3;
    const int schunk = (lane & 7) ^ srow;

    const unsigned short* gA[4];
    const unsigned short* gB[4];
    unsigned short* lA[4];
    unsigned short* lB[4];
    #pragma unroll
    for (int g = 0; g < 4; g++) {
        int r = wv * 32 + g * 8 + srow;
        gA[g] = hb + (size_t)(row0 + r) * Idim + schunk * 8;
        gB[g] = w2b + ((size_t)e * Hdim + ct * 128 + r) * Idim + schunk * 8;
        lA[g] = As + (wv * 32 + g * 8) * BK;
        lB[g] = Bs + (wv * 32 + g * 8) * BK;
    }

    f32x4 acc[4][4] = {};
    const int mrow = (wv & 1) * 64, ncol = (wv >> 1) * 64;
    const int fr = lane & 15, qd = lane >> 4;

    const int k0 = kz * (Idim / SPLITK);
    const int NIT = (Idim / SPLITK) / BK;
    for (int it = 0; it < NIT; it++) {
        #pragma unroll
        for (int g = 0; g < 4; g++) {
            GLD(gA[g] + k0 + it * BK, lA[g]);
            GLD(gB[g] + k0 + it * BK, lB[g]);
        }
        __syncthreads();
        #pragma unroll
        for (int ko = 0; ko < 2; ko++) {
            bf16x8 af[4], bff[4];
            #pragma unroll
            for (int mi = 0; mi < 4; mi++)
                af[mi]  = *(const bf16x8*)&As[(mrow + mi * 16 + fr) * BK + ((((ko << 2) | qd) ^ (fr & 7)) << 3)];
            #pragma unroll
            for (int ni = 0; ni < 4; ni++)
                bff[ni] = *(const bf16x8*)&Bs[(ncol + ni * 16 + fr) * BK + ((((ko << 2) | qd) ^ (fr & 7)) << 3)];
            #pragma unroll
            for (int mi = 0; mi < 4; mi++)
                #pragma unroll
                for (int ni = 0; ni < 4; ni++)
                    acc[mi][ni] = __builtin_amdgcn_mfma_f32_16x16x32_bf16(af[mi], bff[ni], acc[mi][ni], 0, 0, 0);
        }
        __syncthreads();
    }
    // fused combine: out[token] += weight * acc   (fp32 atomics, distinct
    // addresses within a wave-op -> coalesced; <=8 contenders per element)
    #pragma unroll
    for (int mi = 0; mi < 4; mi++) {
        #pragma unroll
        for (int r = 0; r < 4; r++) {
            int row = row0 + mrow + mi * 16 + qd * 4 + r;
            int tk = stok[row];
            float w = swf[row];
            if (tk >= 0) {
                float* op = out + (size_t)tk * Hdim + ct * 128 + ncol + fr;
                #pragma unroll
                for (int ni = 0; ni < 4; ni++)
                    atomicAdd(op + ni * 16, w * acc[mi][ni][r]);
            }
        }
    }
}

extern "C" void kernel_launch(void* const* d_in, const int* in_sizes, int n_in,
                              void* d_out, int out_size, void* d_ws, size_t ws_size,
                              hipStream_t stream) {
    const float* x  = (const float*)d_in[0];   // [2,2048,1024]
    const float* gw = (const float*)d_in[1];   // [8,1024]
    const float* w1 = (const float*)d_in[2];   // [8,4096,1024]
    const float* w2 = (const float*)d_in[3];   // [8,1024,4096]
    float* out = (float*)d_out;

    char* ws = (char*)d_ws;
    unsigned short* w1b = (unsigned short*)(ws + W1B_OFF);
    unsigned short* w2b = (unsigned short*)(ws + W2B_OFF);
    unsigned short* xb  = (unsigned short*)(ws + XB_OFF);
    unsigned short* hb  = (unsigned short*)(ws + HB_OFF);
    int*            meta = (int*)(ws + META_OFF);
    int* counts = meta + M_COUNTS;
    int* curs   = meta + M_CURS;
    int* texp   = meta + M_TEXP;
    int* tslot  = meta + M_TSLOT;
    int* stok   = meta + M_STOK;
    float* twf  = (float*)(meta + M_TWF);
    float* swf  = (float*)(meta + M_SWF);

    cvt_w_k<<<65536, 256, 0, stream>>>(w1, w2, w1b, w2b, NE * Idim * Hdim / 4, meta, out);
    router_k<<<T / 4, 256, 0, stream>>>(x, gw, out + OUT0, texp, twf, counts, xb);
    assign_k<<<32, 256, 0, stream>>>(texp, counts, twf, curs, stok, tslot, swf);
    gemm1_k<<<dim3(Idim / 128, SLOT_CAP / 128), 256, 0, stream>>>(xb, w1b, counts, stok, hb);
    gemm2_k<<<(Hdim / 128) * (SLOT_CAP / 128) * SPLITK, 256, 0, stream>>>(hb, w2b, counts, stok, swf, out);
}

// Round 4
// 630.816 us; speedup vs baseline: 1.0601x; 1.0601x over previous
//
#include <hip/hip_runtime.h>

// ---------------- problem constants ----------------
#define T 4096          // tokens (2*2048)
#define Hdim 1024       // hidden
#define Idim 4096       // intermediate
#define NE 8            // experts
#define OUT0 4194304    // T*Hdim (out elems), logits follow at d_out+OUT0 (T*NE)
#define SPLITK 2        // gemm2 split-K factor (disjoint bf16 partials, no atomics)
#define BK 64           // GEMM K-tile (32 KB LDS total, 2 MFMA k-steps per barrier)

// padded slot capacity: sum ceil(cnt_e/128)*128 <= 8192 + 8*128 = 9216
#define SLOT_CAP 9216

// ---------------- ws layout (bytes) ----------------
// weights are consumed fp32 directly inside the gemms (inline cvt) -> no w1b/w2b copies.
#define XB_OFF  0u                    // bf16 x  [T][H]        8388608
#define HB_OFF  8388608u              // bf16 h  [SLOT_CAP][I] 75497472
#define YB_OFF  83886080u             // bf16 y  [2][SLOT_CAP][H] 37748736
#define META_OFF 121634816u
// meta (int index):
#define M_COUNTS 0      // [8]
#define M_CURS   8      // [8]
#define M_TEXP   32     // [8192] token-pair -> expert
#define M_TSLOT  8224   // [8192] token-pair -> slot
#define M_STOK   16416  // [9216] slot -> token (-1 = pad)
#define M_TWF    25632  // float[8192] token-pair weight (reinterpret)

typedef short bf16x8 __attribute__((ext_vector_type(8)));
typedef float f32x4  __attribute__((ext_vector_type(4)));

__device__ __forceinline__ unsigned short f2bf(float f) {
    unsigned int b = __float_as_uint(f);
    b += 0x7fffu + ((b >> 16) & 1u);      // round-nearest-even
    return (unsigned short)(b >> 16);
}
__device__ __forceinline__ float bf2f(unsigned short s) {
    return __uint_as_float(((unsigned int)s) << 16);
}

// async global->LDS DMA, 16B/lane. LDS dest is wave-uniform base + lane*16
// (m104); layout is linear-in-lane with the XOR swizzle pre-applied to the
// GLOBAL source address (rule #21), so content matches the swizzled ds_read.
#define GLD(gsrc, ldst) \
    __builtin_amdgcn_global_load_lds( \
        (const __attribute__((address_space(1))) unsigned int*)(gsrc), \
        (__attribute__((address_space(3))) unsigned int*)(ldst), 16, 0, 0)

// ---------------- meta init (counts/curs zero, stok = -1) ----------------
__global__ void zero_k(int* meta) {
    int i = blockIdx.x * blockDim.x + threadIdx.x;
    if (i < 16) meta[M_COUNTS + i] = 0;
    if (i < SLOT_CAP) meta[M_STOK + i] = -1;
}

// fp32-exact router: logits, top-2, softmax, counts; also emits xb (bf16 x).
__global__ void router_k(const float* __restrict__ x, const float* __restrict__ gw,
                         float* __restrict__ logits_out, int* __restrict__ texp,
                         float* __restrict__ twf, int* __restrict__ counts,
                         unsigned short* __restrict__ xb) {
    int wv = threadIdx.x >> 6, lane = threadIdx.x & 63;
    int t = blockIdx.x * 4 + wv;
    const float* xp = x + (size_t)t * Hdim;
    unsigned short* xbp = xb + (size_t)t * Hdim;
    float s[NE];
    #pragma unroll
    for (int e = 0; e < NE; e++) s[e] = 0.f;
    #pragma unroll
    for (int j = 0; j < 16; j++) {
        float xv = xp[lane + 64 * j];
        xbp[lane + 64 * j] = f2bf(xv);
        #pragma unroll
        for (int e = 0; e < NE; e++) s[e] += xv * gw[e * Hdim + lane + 64 * j];
    }
    #pragma unroll
    for (int e = 0; e < NE; e++) {
        #pragma unroll
        for (int off = 32; off > 0; off >>= 1) s[e] += __shfl_xor(s[e], off);
    }
    if (lane == 0) {
        #pragma unroll
        for (int e = 0; e < NE; e++) logits_out[t * NE + e] = s[e];
        int i0 = 0; float v0 = s[0];
        #pragma unroll
        for (int e = 1; e < NE; e++) if (s[e] > v0) { v0 = s[e]; i0 = e; }
        int i1 = -1; float v1 = -3.4e38f;
        #pragma unroll
        for (int e = 0; e < NE; e++) if (e != i0 && s[e] > v1) { v1 = s[e]; i1 = e; }
        float e1 = expf(v1 - v0);            // v1<=v0, stable
        float inv = 1.f / (1.f + e1);
        texp[2 * t] = i0; texp[2 * t + 1] = i1;
        twf[2 * t] = inv; twf[2 * t + 1] = e1 * inv;
        atomicAdd(&counts[i0], 1);
        atomicAdd(&counts[i1], 1);
    }
}

// padded prefix-sum over counts computed inline (deterministic, identical
// formula everywhere) -- no serial offsets kernel.
__global__ void assign_k(const int* __restrict__ texp, const int* __restrict__ counts,
                         int* __restrict__ curs, int* __restrict__ stok, int* __restrict__ tslot) {
    int p = blockIdx.x * blockDim.x + threadIdx.x;  // pair id < 8192
    int e = texp[p];
    int off = 0;
    #pragma unroll
    for (int q = 0; q < NE; q++) {
        int pc = (counts[q] + 127) & ~127;
        off += (q < e) ? pc : 0;
    }
    int slot = off + atomicAdd(&curs[e], 1);
    stok[slot] = p >> 1;
    tslot[p] = slot;
}

// B-side fp32 prefetch into named regs (no arrays -> no scratch, rule #20).
// Loads for tile it+1 are issued at TOP of compute phase of tile it (in
// flight behind ds_read+MFMA, round-0's proven skeleton); converted to bf16
// (same RNE f2bf -> weights bit-identical to the old cvt_w path) and
// ds_write_b128'd after the barrier.
#define LOADB(off) \
    b00 = *(const float4*)(gB0 + (off)); b01 = *(const float4*)(gB0 + (off) + 4); \
    b10 = *(const float4*)(gB1 + (off)); b11 = *(const float4*)(gB1 + (off) + 4); \
    b20 = *(const float4*)(gB2 + (off)); b21 = *(const float4*)(gB2 + (off) + 4); \
    b30 = *(const float4*)(gB3 + (off)); b31 = *(const float4*)(gB3 + (off) + 4);
#define PK2(lo, hi) (((unsigned)f2bf(lo)) | (((unsigned)f2bf(hi)) << 16))
#define CVTSTOREB() { uint4 q; \
    q.x = PK2(b00.x, b00.y); q.y = PK2(b00.z, b00.w); \
    q.z = PK2(b01.x, b01.y); q.w = PK2(b01.z, b01.w); *(uint4*)lb0 = q; \
    q.x = PK2(b10.x, b10.y); q.y = PK2(b10.z, b10.w); \
    q.z = PK2(b11.x, b11.y); q.w = PK2(b11.z, b11.w); *(uint4*)lb1 = q; \
    q.x = PK2(b20.x, b20.y); q.y = PK2(b20.z, b20.w); \
    q.z = PK2(b21.x, b21.y); q.w = PK2(b21.z, b21.w); *(uint4*)lb2 = q; \
    q.x = PK2(b30.x, b30.y); q.y = PK2(b30.z, b30.w); \
    q.z = PK2(b31.x, b31.y); q.w = PK2(b31.z, b31.w); *(uint4*)lb3 = q; }

// ---------------- grouped GEMM1: h = gelu(x @ w1[e]^T), bf16 out ----------------
// A (tokens, bf16 xb): async global->LDS DMA. B (weights): fp32 direct from
// d_in with inline cvt -> deletes the 62 us cvt_w pass + 128 MB of copies.
__global__ __launch_bounds__(256, 3) void gemm1_k(
    const unsigned short* __restrict__ xb, const float* __restrict__ w1,
    const int* __restrict__ counts, const int* __restrict__ stok,
    unsigned short* __restrict__ hb) {
    __shared__ __align__(16) unsigned short As[128 * BK];
    __shared__ __align__(16) unsigned short Bs[128 * BK];
    const int rt = blockIdx.y, ct = blockIdx.x;
    const int row0 = rt * 128;
    int offs[NE + 1];
    offs[0] = 0;
    #pragma unroll
    for (int q = 0; q < NE; q++) offs[q + 1] = offs[q] + ((counts[q] + 127) & ~127);
    if (row0 >= offs[NE]) return;
    int e = 0;
    #pragma unroll
    for (int q = 1; q < NE; q++) if (offs[q] <= row0) e = q;

    const int tid = threadIdx.x;
    const int lane = tid & 63, wv = tid >> 6;
    const int srow = lane >> 3;                 // row within 8-row staging group
    const int schunk = (lane & 7) ^ srow;       // swizzled source k-chunk (8 elems)

    const unsigned short* gA[4];
    unsigned short* lA[4];
    #pragma unroll
    for (int g = 0; g < 4; g++) {
        int r = wv * 32 + g * 8 + srow;
        int t = stok[row0 + r]; if (t < 0) t = 0;
        gA[g] = xb + (size_t)t * Hdim + schunk * 8;
        lA[g] = As + (wv * 32 + g * 8) * BK;    // wave-uniform LDS base
    }
    int rB0 = wv * 32 + 0 * 8 + srow, rB1 = wv * 32 + 1 * 8 + srow;
    int rB2 = wv * 32 + 2 * 8 + srow, rB3 = wv * 32 + 3 * 8 + srow;
    const float* gB0 = w1 + ((size_t)e * Idim + ct * 128 + rB0) * Hdim + schunk * 8;
    const float* gB1 = w1 + ((size_t)e * Idim + ct * 128 + rB1) * Hdim + schunk * 8;
    const float* gB2 = w1 + ((size_t)e * Idim + ct * 128 + rB2) * Hdim + schunk * 8;
    const float* gB3 = w1 + ((size_t)e * Idim + ct * 128 + rB3) * Hdim + schunk * 8;
    unsigned short* lb0 = Bs + (wv * 32 + 0 * 8) * BK + lane * 8;
    unsigned short* lb1 = Bs + (wv * 32 + 1 * 8) * BK + lane * 8;
    unsigned short* lb2 = Bs + (wv * 32 + 2 * 8) * BK + lane * 8;
    unsigned short* lb3 = Bs + (wv * 32 + 3 * 8) * BK + lane * 8;

    f32x4 acc[4][4] = {};
    const int mrow = (wv & 1) * 64, ncol = (wv >> 1) * 64;
    const int fr = lane & 15, qd = lane >> 4;

    float4 b00, b01, b10, b11, b20, b21, b30, b31;
    // prologue: stage tile 0
    #pragma unroll
    for (int g = 0; g < 4; g++) GLD(gA[g], lA[g]);
    LOADB(0)
    CVTSTOREB()
    __syncthreads();

    const int NIT = Hdim / BK;
    for (int it = 0; it < NIT; it++) {
        if (it + 1 < NIT) { LOADB((it + 1) * BK) }   // fp32 B in flight during compute
        #pragma unroll
        for (int ko = 0; ko < 2; ko++) {
            bf16x8 af[4], bff[4];
            #pragma unroll
            for (int mi = 0; mi < 4; mi++)
                af[mi]  = *(const bf16x8*)&As[(mrow + mi * 16 + fr) * BK + ((((ko << 2) | qd) ^ (fr & 7)) << 3)];
            #pragma unroll
            for (int ni = 0; ni < 4; ni++)
                bff[ni] = *(const bf16x8*)&Bs[(ncol + ni * 16 + fr) * BK + ((((ko << 2) | qd) ^ (fr & 7)) << 3)];
            #pragma unroll
            for (int mi = 0; mi < 4; mi++)
                #pragma unroll
                for (int ni = 0; ni < 4; ni++)
                    acc[mi][ni] = __builtin_amdgcn_mfma_f32_16x16x32_bf16(af[mi], bff[ni], acc[mi][ni], 0, 0, 0);
        }
        if (it + 1 < NIT) {
            __syncthreads();                  // all waves done reading tile it
            #pragma unroll
            for (int g = 0; g < 4; g++) GLD(gA[g] + (it + 1) * BK, lA[g]);
            CVTSTOREB()                        // waits only on B loads (older vmcnt)
            __syncthreads();                  // drains A-DMA + B ds_write
        }
    }
    // epilogue: tanh-form gelu (sigmoid identity) -> bf16.
    #pragma unroll
    for (int mi = 0; mi < 4; mi++) {
        #pragma unroll
        for (int ni = 0; ni < 4; ni++) {
            #pragma unroll
            for (int r = 0; r < 4; r++) {
                int row = row0 + mrow + mi * 16 + qd * 4 + r;
                int col = ct * 128 + ncol + ni * 16 + fr;
                float v = acc[mi][ni][r];
                float u = v * (1.f + 0.044715f * v * v);
                float g = v / (1.f + __expf(-1.5957691216f * u));
                hb[(size_t)row * Idim + col] = f2bf(g);
            }
        }
    }
}

// ---------------- grouped GEMM2 (split-K, disjoint bf16 partials) ----------------
// 1D grid 1152, XCD-territory decode: XCD k = id%8 owns rt in [9k, 9k+9) for
// all (ct, kz). A = hb via DMA; B = w2 fp32 with inline cvt.
__global__ __launch_bounds__(256, 3) void gemm2_k(
    const unsigned short* __restrict__ hb, const float* __restrict__ w2,
    const int* __restrict__ counts, unsigned short* __restrict__ y16) {
    __shared__ __align__(16) unsigned short As[128 * BK];
    __shared__ __align__(16) unsigned short Bs[128 * BK];
    const int id = blockIdx.x;
    const int k8 = id & 7;                 // intended XCD
    const int j  = id >> 3;                // per-XCD sequence 0..143
    const int ct = j & 7;                  // B col tile
    const int j8 = j >> 3;                 // 0..17
    const int rtL = j8 % 9, kz = j8 / 9;
    const int rt = k8 * 9 + rtL;
    const int row0 = rt * 128;
    int offs[NE + 1];
    offs[0] = 0;
    #pragma unroll
    for (int q = 0; q < NE; q++) offs[q + 1] = offs[q] + ((counts[q] + 127) & ~127);
    if (row0 >= offs[NE]) return;
    int e = 0;
    #pragma unroll
    for (int q = 1; q < NE; q++) if (offs[q] <= row0) e = q;

    const int tid = threadIdx.x;
    const int lane = tid & 63, wv = tid >> 6;
    const int srow = lane >> 3;
    const int schunk = (lane & 7) ^ srow;

    const unsigned short* gA[4];
    unsigned short* lA[4];
    #pragma unroll
    for (int g = 0; g < 4; g++) {
        int r = wv * 32 + g * 8 + srow;
        gA[g] = hb + (size_t)(row0 + r) * Idim + schunk * 8;
        lA[g] = As + (wv * 32 + g * 8) * BK;
    }
    int rB0 = wv * 32 + 0 * 8 + srow, rB1 = wv * 32 + 1 * 8 + srow;
    int rB2 = wv * 32 + 2 * 8 + srow, rB3 = wv * 32 + 3 * 8 + srow;
    const float* gB0 = w2 + ((size_t)e * Hdim + ct * 128 + rB0) * Idim + schunk * 8;
    const float* gB1 = w2 + ((size_t)e * Hdim + ct * 128 + rB1) * Idim + schunk * 8;
    const float* gB2 = w2 + ((size_t)e * Hdim + ct * 128 + rB2) * Idim + schunk * 8;
    const float* gB3 = w2 + ((size_t)e * Hdim + ct * 128 + rB3) * Idim + schunk * 8;
    unsigned short* lb0 = Bs + (wv * 32 + 0 * 8) * BK + lane * 8;
    unsigned short* lb1 = Bs + (wv * 32 + 1 * 8) * BK + lane * 8;
    unsigned short* lb2 = Bs + (wv * 32 + 2 * 8) * BK + lane * 8;
    unsigned short* lb3 = Bs + (wv * 32 + 3 * 8) * BK + lane * 8;

    f32x4 acc[4][4] = {};
    const int mrow = (wv & 1) * 64, ncol = (wv >> 1) * 64;
    const int fr = lane & 15, qd = lane >> 4;

    const int k0 = kz * (Idim / SPLITK);
    float4 b00, b01, b10, b11, b20, b21, b30, b31;
    #pragma unroll
    for (int g = 0; g < 4; g++) GLD(gA[g] + k0, lA[g]);
    LOADB(k0)
    CVTSTOREB()
    __syncthreads();

    const int NIT = (Idim / SPLITK) / BK;
    for (int it = 0; it < NIT; it++) {
        if (it + 1 < NIT) { LOADB(k0 + (it + 1) * BK) }
        #pragma unroll
        for (int ko = 0; ko < 2; ko++) {
            bf16x8 af[4], bff[4];
            #pragma unroll
            for (int mi = 0; mi < 4; mi++)
                af[mi]  = *(const bf16x8*)&As[(mrow + mi * 16 + fr) * BK + ((((ko << 2) | qd) ^ (fr & 7)) << 3)];
            #pragma unroll
            for (int ni = 0; ni < 4; ni++)
                bff[ni] = *(const bf16x8*)&Bs[(ncol + ni * 16 + fr) * BK + ((((ko << 2) | qd) ^ (fr & 7)) << 3)];
            #pragma unroll
            for (int mi = 0; mi < 4; mi++)
                #pragma unroll
                for (int ni = 0; ni < 4; ni++)
                    acc[mi][ni] = __builtin_amdgcn_mfma_f32_16x16x32_bf16(af[mi], bff[ni], acc[mi][ni], 0, 0, 0);
        }
        if (it + 1 < NIT) {
            __syncthreads();
            #pragma unroll
            for (int g = 0; g < 4; g++) GLD(gA[g] + k0 + (it + 1) * BK, lA[g]);
            CVTSTOREB()
            __syncthreads();
        }
    }
    unsigned short* yk = y16 + (size_t)kz * SLOT_CAP * Hdim;
    #pragma unroll
    for (int mi = 0; mi < 4; mi++) {
        #pragma unroll
        for (int ni = 0; ni < 4; ni++) {
            #pragma unroll
            for (int r = 0; r < 4; r++) {
                int row = row0 + mrow + mi * 16 + qd * 4 + r;
                int col = ct * 128 + ncol + ni * 16 + fr;
                yk[(size_t)row * Hdim + col] = f2bf(acc[mi][ni][r]);
            }
        }
    }
}

// out[t] = w0 * (y0[s0]+y1[s0]) + w1 * (y0[s1]+y1[s1])   (bf16 partials, fused reduce)
__global__ void combine_k(const unsigned short* __restrict__ y16, const int* __restrict__ tslot,
                          const float* __restrict__ twf, float* __restrict__ out) {
    int i = blockIdx.x * blockDim.x + threadIdx.x;   // < T*H/8
    int t = i >> 7, rem = i & 127;                   // H/8 = 128
    int s0 = tslot[2 * t], s1 = tslot[2 * t + 1];
    float w0 = twf[2 * t], w1 = twf[2 * t + 1];
    const uint4* y0 = (const uint4*)(y16);
    const uint4* y1 = (const uint4*)(y16 + (size_t)SLOT_CAP * Hdim);
    uint4 a0 = y0[(size_t)s0 * 128 + rem];
    uint4 a1 = y1[(size_t)s0 * 128 + rem];
    uint4 b0 = y0[(size_t)s1 * 128 + rem];
    uint4 b1 = y1[(size_t)s1 * 128 + rem];
    float o[8];
    #pragma unroll
    for (int j = 0; j < 4; j++) {
        unsigned int ua0 = ((const unsigned int*)&a0)[j], ua1 = ((const unsigned int*)&a1)[j];
        unsigned int ub0 = ((const unsigned int*)&b0)[j], ub1 = ((const unsigned int*)&b1)[j];
        float alo = bf2f((unsigned short)ua0) + bf2f((unsigned short)ua1);
        float ahi = bf2f((unsigned short)(ua0 >> 16)) + bf2f((unsigned short)(ua1 >> 16));
        float blo = bf2f((unsigned short)ub0) + bf2f((unsigned short)ub1);
        float bhi = bf2f((unsigned short)(ub0 >> 16)) + bf2f((unsigned short)(ub1 >> 16));
        o[2 * j]     = w0 * alo + w1 * blo;
        o[2 * j + 1] = w0 * ahi + w1 * bhi;
    }
    float4* out4 = (float4*)out;
    out4[2 * i]     = make_float4(o[0], o[1], o[2], o[3]);
    out4[2 * i + 1] = make_float4(o[4], o[5], o[6], o[7]);
}

extern "C" void kernel_launch(void* const* d_in, const int* in_sizes, int n_in,
                              void* d_out, int out_size, void* d_ws, size_t ws_size,
                              hipStream_t stream) {
    const float* x  = (const float*)d_in[0];   // [2,2048,1024]
    const float* gw = (const float*)d_in[1];   // [8,1024]
    const float* w1 = (const float*)d_in[2];   // [8,4096,1024]
    const float* w2 = (const float*)d_in[3];   // [8,1024,4096]
    float* out = (float*)d_out;

    char* ws = (char*)d_ws;
    unsigned short* xb  = (unsigned short*)(ws + XB_OFF);
    unsigned short* hb  = (unsigned short*)(ws + HB_OFF);
    unsigned short* y16 = (unsigned short*)(ws + YB_OFF);
    int*            meta = (int*)(ws + META_OFF);
    int* counts = meta + M_COUNTS;
    int* curs   = meta + M_CURS;
    int* texp   = meta + M_TEXP;
    int* tslot  = meta + M_TSLOT;
    int* stok   = meta + M_STOK;
    float* twf  = (float*)(meta + M_TWF);

    zero_k<<<36, 256, 0, stream>>>(meta);
    router_k<<<T / 4, 256, 0, stream>>>(x, gw, out + OUT0, texp, twf, counts, xb);
    assign_k<<<32, 256, 0, stream>>>(texp, counts, curs, stok, tslot);
    gemm1_k<<<dim3(Idim / 128, SLOT_CAP / 128), 256, 0, stream>>>(xb, w1, counts, stok, hb);
    gemm2_k<<<(Hdim / 128) * (SLOT_CAP / 128) * SPLITK, 256, 0, stream>>>(hb, w2, counts, y16);
    combine_k<<<T * Hdim / 8 / 256, 256, 0, stream>>>(y16, tslot, twf, out);
}

// Round 5
// 616.937 us; speedup vs baseline: 1.0839x; 1.0225x over previous
//
#include <hip/hip_runtime.h>

// ---------------- problem constants ----------------
#define T 4096          // tokens (2*2048)
#define Hdim 1024       // hidden
#define Idim 4096       // intermediate
#define NE 8            // experts
#define OUT0 4194304    // T*Hdim (out elems), logits follow at d_out+OUT0 (T*NE)
#define SPLITK 4        // gemm2 split-K (disjoint bf16 partials; grid 2304 = exact 3 occupancy rounds)
#define BK 64           // GEMM K-tile (32 KB LDS total, 2 MFMA k-steps per barrier)

// padded slot capacity: sum ceil(cnt_e/128)*128 <= 8192 + 8*128 = 9216
#define SLOT_CAP 9216

// ---------------- ws layout (bytes) ----------------
// NOTE: y partials kz=2,3 ALIAS the w1b/xb region (dead after gemm1; stream
// order guarantees gemm1 done before gemm2 writes; cvt_w rewrites w1b next
// iteration before any reader). Keeps total footprint at the proven ~256 MB.
#define W1B_OFF 0u                    // bf16 w1 [E][I][H]   67108864   (aliased by y[2],y[3] later)
#define XB_OFF  67108864u             // bf16 x  [T][H]       8388608
#define W2B_OFF 75497472u             // bf16 w2 [E][H][I]   67108864
#define HB_OFF  142606336u            // bf16 h  [SLOT_CAP][I] 75497472
#define YA_OFF  218103808u            // bf16 y  [2][SLOT_CAP][H] 37748736  (kz 0,1)
#define YB_OFF  0u                    // bf16 y  [2][SLOT_CAP][H] (kz 2,3) aliases W1B
#define META_OFF 255852544u
// meta (int index):
#define M_COUNTS 0      // [8]
#define M_CURS   8      // [8]
#define M_TEXP   32     // [8192] token-pair -> expert
#define M_TSLOT  8224   // [8192] token-pair -> slot
#define M_STOK   16416  // [9216] slot -> token (-1 = pad)
#define M_TWF    25632  // float[8192] token-pair weight (reinterpret)

typedef short bf16x8 __attribute__((ext_vector_type(8)));
typedef float f32x4  __attribute__((ext_vector_type(4)));

__device__ __forceinline__ unsigned short f2bf(float f) {
    unsigned int b = __float_as_uint(f);
    b += 0x7fffu + ((b >> 16) & 1u);      // round-nearest-even
    return (unsigned short)(b >> 16);
}
__device__ __forceinline__ float bf2f(unsigned short s) {
    return __uint_as_float(((unsigned int)s) << 16);
}

// async global->LDS DMA, 16B/lane. LDS dest is wave-uniform base + lane*16
// (m104); layout is linear-in-lane with the XOR swizzle pre-applied to the
// GLOBAL source address (rule #21), so content matches the swizzled ds_read.
#define GLD(gsrc, ldst) \
    __builtin_amdgcn_global_load_lds( \
        (const __attribute__((address_space(1))) unsigned int*)(gsrc), \
        (__attribute__((address_space(3))) unsigned int*)(ldst), 16, 0, 0)

// one launch converts both weight tensors fp32->bf16; also zeroes meta
// (counts/curs, stok pad markers) -- disjoint writes, all happen-before
// router_k via stream order.
__global__ void cvt_w_k(const float* __restrict__ w1, const float* __restrict__ w2,
                        unsigned short* __restrict__ w1b, unsigned short* __restrict__ w2b,
                        int n4each, int* __restrict__ meta) {
    int i = blockIdx.x * blockDim.x + threadIdx.x;
    if (i < 16) meta[M_COUNTS + i] = 0;          // counts + cursors
    if (i < SLOT_CAP) meta[M_STOK + i] = -1;     // slot_token pad marker
    const float4* src; ushort4* dst; int j;
    if (i < n4each) { src = (const float4*)w1; dst = (ushort4*)w1b; j = i; }
    else            { src = (const float4*)w2; dst = (ushort4*)w2b; j = i - n4each; }
    float4 v = src[j];
    ushort4 o;
    o.x = f2bf(v.x); o.y = f2bf(v.y); o.z = f2bf(v.z); o.w = f2bf(v.w);
    dst[j] = o;
}

// fp32-exact router: logits, top-2, softmax, counts; also emits xb (bf16 x).
__global__ void router_k(const float* __restrict__ x, const float* __restrict__ gw,
                         float* __restrict__ logits_out, int* __restrict__ texp,
                         float* __restrict__ twf, int* __restrict__ counts,
                         unsigned short* __restrict__ xb) {
    int wv = threadIdx.x >> 6, lane = threadIdx.x & 63;
    int t = blockIdx.x * 4 + wv;
    const float* xp = x + (size_t)t * Hdim;
    unsigned short* xbp = xb + (size_t)t * Hdim;
    float s[NE];
    #pragma unroll
    for (int e = 0; e < NE; e++) s[e] = 0.f;
    #pragma unroll
    for (int j = 0; j < 16; j++) {
        float xv = xp[lane + 64 * j];
        xbp[lane + 64 * j] = f2bf(xv);
        #pragma unroll
        for (int e = 0; e < NE; e++) s[e] += xv * gw[e * Hdim + lane + 64 * j];
    }
    #pragma unroll
    for (int e = 0; e < NE; e++) {
        #pragma unroll
        for (int off = 32; off > 0; off >>= 1) s[e] += __shfl_xor(s[e], off);
    }
    if (lane == 0) {
        #pragma unroll
        for (int e = 0; e < NE; e++) logits_out[t * NE + e] = s[e];
        int i0 = 0; float v0 = s[0];
        #pragma unroll
        for (int e = 1; e < NE; e++) if (s[e] > v0) { v0 = s[e]; i0 = e; }
        int i1 = -1; float v1 = -3.4e38f;
        #pragma unroll
        for (int e = 0; e < NE; e++) if (e != i0 && s[e] > v1) { v1 = s[e]; i1 = e; }
        float e1 = expf(v1 - v0);            // v1<=v0, stable
        float inv = 1.f / (1.f + e1);
        texp[2 * t] = i0; texp[2 * t + 1] = i1;
        twf[2 * t] = inv; twf[2 * t + 1] = e1 * inv;
        atomicAdd(&counts[i0], 1);
        atomicAdd(&counts[i1], 1);
    }
}

// padded prefix-sum over counts computed inline (deterministic, identical
// formula everywhere) -- no serial offsets kernel.
__global__ void assign_k(const int* __restrict__ texp, const int* __restrict__ counts,
                         int* __restrict__ curs, int* __restrict__ stok, int* __restrict__ tslot) {
    int p = blockIdx.x * blockDim.x + threadIdx.x;  // pair id < 8192
    int e = texp[p];
    int off = 0;
    #pragma unroll
    for (int q = 0; q < NE; q++) {
        int pc = (counts[q] + 127) & ~127;
        off += (q < e) ? pc : 0;
    }
    int slot = off + atomicAdd(&curs[e], 1);
    stok[slot] = p >> 1;
    tslot[p] = slot;
}

// ---------------- grouped GEMM1: h = gelu(x @ w1[e]^T), bf16 out ----------------
// Direct async global->LDS DMA; XOR swizzle pre-applied to per-lane GLOBAL
// address; linear LDS dest. 1D grid 2304 with XCD-territory decode: XCD k
// owns rt in [9k,9k+9); within an XCD, ct varies fastest so the A-panel (xb
// rows of one rt) stays L2-resident across its 32 consumers.
__global__ __launch_bounds__(256, 3) void gemm1_k(
    const unsigned short* __restrict__ xb, const unsigned short* __restrict__ w1b,
    const int* __restrict__ counts, const int* __restrict__ stok,
    unsigned short* __restrict__ hb) {
    __shared__ __align__(16) unsigned short As[128 * BK];
    __shared__ __align__(16) unsigned short Bs[128 * BK];
    const int id = blockIdx.x;
    const int k8 = id & 7;                 // intended XCD
    const int j  = id >> 3;                // 0..287
    const int ct = j & 31;                 // B col tile (Idim/128 = 32)
    const int rtL = j >> 5;                // 0..8
    const int rt = k8 * 9 + rtL;
    const int row0 = rt * 128;
    int offs[NE + 1];
    offs[0] = 0;
    #pragma unroll
    for (int q = 0; q < NE; q++) offs[q + 1] = offs[q] + ((counts[q] + 127) & ~127);
    if (row0 >= offs[NE]) return;
    int e = 0;
    #pragma unroll
    for (int q = 1; q < NE; q++) if (offs[q] <= row0) e = q;

    const int tid = threadIdx.x;
    const int lane = tid & 63, wv = tid >> 6;
    const int srow = lane >> 3;                 // row within 8-row staging group
    const int schunk = (lane & 7) ^ srow;       // swizzled source k-chunk (8 bf16)

    const unsigned short* gA[4];
    const unsigned short* gB[4];
    unsigned short* lA[4];
    unsigned short* lB[4];
    #pragma unroll
    for (int g = 0; g < 4; g++) {
        int r = wv * 32 + g * 8 + srow;
        int t = stok[row0 + r]; if (t < 0) t = 0;
        gA[g] = xb + (size_t)t * Hdim + schunk * 8;
        gB[g] = w1b + ((size_t)e * Idim + ct * 128 + r) * Hdim + schunk * 8;
        lA[g] = As + (wv * 32 + g * 8) * BK;    // wave-uniform LDS base
        lB[g] = Bs + (wv * 32 + g * 8) * BK;
    }

    f32x4 acc[4][4] = {};
    const int mrow = (wv & 1) * 64, ncol = (wv >> 1) * 64;
    const int fr = lane & 15, qd = lane >> 4;

    const int NIT = Hdim / BK;
    for (int it = 0; it < NIT; it++) {
        #pragma unroll
        for (int g = 0; g < 4; g++) {
            GLD(gA[g] + it * BK, lA[g]);
            GLD(gB[g] + it * BK, lB[g]);
        }
        __syncthreads();                      // vmcnt(0) drain -> tile resident
        #pragma unroll
        for (int ko = 0; ko < 2; ko++) {
            bf16x8 af[4], bff[4];
            #pragma unroll
            for (int mi = 0; mi < 4; mi++)
                af[mi]  = *(const bf16x8*)&As[(mrow + mi * 16 + fr) * BK + ((((ko << 2) | qd) ^ (fr & 7)) << 3)];
            #pragma unroll
            for (int ni = 0; ni < 4; ni++)
                bff[ni] = *(const bf16x8*)&Bs[(ncol + ni * 16 + fr) * BK + ((((ko << 2) | qd) ^ (fr & 7)) << 3)];
            #pragma unroll
            for (int mi = 0; mi < 4; mi++)
                #pragma unroll
                for (int ni = 0; ni < 4; ni++)
                    acc[mi][ni] = __builtin_amdgcn_mfma_f32_16x16x32_bf16(af[mi], bff[ni], acc[mi][ni], 0, 0, 0);
        }
        __syncthreads();                      // waves done reading before overwrite
    }
    // epilogue: tanh-form gelu (sigmoid identity) -> bf16.
    #pragma unroll
    for (int mi = 0; mi < 4; mi++) {
        #pragma unroll
        for (int ni = 0; ni < 4; ni++) {
            #pragma unroll
            for (int r = 0; r < 4; r++) {
                int row = row0 + mrow + mi * 16 + qd * 4 + r;
                int col = ct * 128 + ncol + ni * 16 + fr;
                float v = acc[mi][ni][r];
                float u = v * (1.f + 0.044715f * v * v);
                float g = v / (1.f + __expf(-1.5957691216f * u));
                hb[(size_t)row * Idim + col] = f2bf(g);
            }
        }
    }
}

// ---------------- grouped GEMM2 (split-K=4, disjoint bf16 partials) ----------------
// 1D grid 2304 = exactly 3 occupancy rounds at 3 blocks/CU (the SPLITK=2 grid
// of 1152 was 1.5 rounds -> 25% capacity wasted in the half-empty round).
// XCD-territory decode: XCD k = id%8 owns rt in [9k, 9k+9) for all (ct, kz).
// Partials kz 0,1 -> ya; kz 2,3 -> yb (aliases dead w1b region).
__global__ __launch_bounds__(256, 3) void gemm2_k(
    const unsigned short* __restrict__ hb, const unsigned short* __restrict__ w2b,
    const int* __restrict__ counts, unsigned short* __restrict__ ya,
    unsigned short* __restrict__ yb) {
    __shared__ __align__(16) unsigned short As[128 * BK];
    __shared__ __align__(16) unsigned short Bs[128 * BK];
    const int id = blockIdx.x;
    const int k8 = id & 7;                 // intended XCD
    const int j  = id >> 3;                // per-XCD sequence 0..287
    const int ct = j & 7;                  // B col tile (Hdim/128 = 8)
    const int j8 = j >> 3;                 // 0..35
    const int rtL = j8 % 9, kz = j8 / 9;   // kz in 0..3
    const int rt = k8 * 9 + rtL;
    const int row0 = rt * 128;
    int offs[NE + 1];
    offs[0] = 0;
    #pragma unroll
    for (int q = 0; q < NE; q++) offs[q + 1] = offs[q] + ((counts[q] + 127) & ~127);
    if (row0 >= offs[NE]) return;
    int e = 0;
    #pragma unroll
    for (int q = 1; q < NE; q++) if (offs[q] <= row0) e = q;

    const int tid = threadIdx.x;
    const int lane = tid & 63, wv = tid >> 6;
    const int srow = lane >> 3;
    const int schunk = (lane & 7) ^ srow;

    const unsigned short* gA[4];
    const unsigned short* gB[4];
    unsigned short* lA[4];
    unsigned short* lB[4];
    #pragma unroll
    for (int g = 0; g < 4; g++) {
        int r = wv * 32 + g * 8 + srow;
        gA[g] = hb + (size_t)(row0 + r) * Idim + schunk * 8;
        gB[g] = w2b + ((size_t)e * Hdim + ct * 128 + r) * Idim + schunk * 8;
        lA[g] = As + (wv * 32 + g * 8) * BK;
        lB[g] = Bs + (wv * 32 + g * 8) * BK;
    }

    f32x4 acc[4][4] = {};
    const int mrow = (wv & 1) * 64, ncol = (wv >> 1) * 64;
    const int fr = lane & 15, qd = lane >> 4;

    const int k0 = kz * (Idim / SPLITK);
    const int NIT = (Idim / SPLITK) / BK;
    for (int it = 0; it < NIT; it++) {
        #pragma unroll
        for (int g = 0; g < 4; g++) {
            GLD(gA[g] + k0 + it * BK, lA[g]);
            GLD(gB[g] + k0 + it * BK, lB[g]);
        }
        __syncthreads();
        #pragma unroll
        for (int ko = 0; ko < 2; ko++) {
            bf16x8 af[4], bff[4];
            #pragma unroll
            for (int mi = 0; mi < 4; mi++)
                af[mi]  = *(const bf16x8*)&As[(mrow + mi * 16 + fr) * BK + ((((ko << 2) | qd) ^ (fr & 7)) << 3)];
            #pragma unroll
            for (int ni = 0; ni < 4; ni++)
                bff[ni] = *(const bf16x8*)&Bs[(ncol + ni * 16 + fr) * BK + ((((ko << 2) | qd) ^ (fr & 7)) << 3)];
            #pragma unroll
            for (int mi = 0; mi < 4; mi++)
                #pragma unroll
                for (int ni = 0; ni < 4; ni++)
                    acc[mi][ni] = __builtin_amdgcn_mfma_f32_16x16x32_bf16(af[mi], bff[ni], acc[mi][ni], 0, 0, 0);
        }
        __syncthreads();
    }
    unsigned short* yk = (kz < 2) ? (ya + (size_t)kz * SLOT_CAP * Hdim)
                                  : (yb + (size_t)(kz - 2) * SLOT_CAP * Hdim);
    #pragma unroll
    for (int mi = 0; mi < 4; mi++) {
        #pragma unroll
        for (int ni = 0; ni < 4; ni++) {
            #pragma unroll
            for (int r = 0; r < 4; r++) {
                int row = row0 + mrow + mi * 16 + qd * 4 + r;
                int col = ct * 128 + ncol + ni * 16 + fr;
                yk[(size_t)row * Hdim + col] = f2bf(acc[mi][ni][r]);
            }
        }
    }
}

// out[t] = w0 * sum_k yk[s0] + w1 * sum_k yk[s1]   (4 bf16 partials, fused reduce)
__global__ void combine_k(const unsigned short* __restrict__ ya, const unsigned short* __restrict__ yb,
                          const int* __restrict__ tslot, const float* __restrict__ twf,
                          float* __restrict__ out) {
    int i = blockIdx.x * blockDim.x + threadIdx.x;   // < T*H/8
    int t = i >> 7, rem = i & 127;                   // H/8 = 128
    int s0 = tslot[2 * t], s1 = tslot[2 * t + 1];
    float w0 = twf[2 * t], w1 = twf[2 * t + 1];
    const uint4* y0 = (const uint4*)(ya);
    const uint4* y1 = (const uint4*)(ya + (size_t)SLOT_CAP * Hdim);
    const uint4* y2 = (const uint4*)(yb);
    const uint4* y3 = (const uint4*)(yb + (size_t)SLOT_CAP * Hdim);
    uint4 a0 = y0[(size_t)s0 * 128 + rem];
    uint4 a1 = y1[(size_t)s0 * 128 + rem];
    uint4 a2 = y2[(size_t)s0 * 128 + rem];
    uint4 a3 = y3[(size_t)s0 * 128 + rem];
    uint4 b0 = y0[(size_t)s1 * 128 + rem];
    uint4 b1 = y1[(size_t)s1 * 128 + rem];
    uint4 b2 = y2[(size_t)s1 * 128 + rem];
    uint4 b3 = y3[(size_t)s1 * 128 + rem];
    float o[8];
    #pragma unroll
    for (int j = 0; j < 4; j++) {
        unsigned int ua0 = ((const unsigned int*)&a0)[j], ua1 = ((const unsigned int*)&a1)[j];
        unsigned int ua2 = ((const unsigned int*)&a2)[j], ua3 = ((const unsigned int*)&a3)[j];
        unsigned int ub0 = ((const unsigned int*)&b0)[j], ub1 = ((const unsigned int*)&b1)[j];
        unsigned int ub2 = ((const unsigned int*)&b2)[j], ub3 = ((const unsigned int*)&b3)[j];
        float alo = (bf2f((unsigned short)ua0) + bf2f((unsigned short)ua1))
                  + (bf2f((unsigned short)ua2) + bf2f((unsigned short)ua3));
        float ahi = (bf2f((unsigned short)(ua0 >> 16)) + bf2f((unsigned short)(ua1 >> 16)))
                  + (bf2f((unsigned short)(ua2 >> 16)) + bf2f((unsigned short)(ua3 >> 16)));
        float blo = (bf2f((unsigned short)ub0) + bf2f((unsigned short)ub1))
                  + (bf2f((unsigned short)ub2) + bf2f((unsigned short)ub3));
        float bhi = (bf2f((unsigned short)(ub0 >> 16)) + bf2f((unsigned short)(ub1 >> 16)))
                  + (bf2f((unsigned short)(ub2 >> 16)) + bf2f((unsigned short)(ub3 >> 16)));
        o[2 * j]     = w0 * alo + w1 * blo;
        o[2 * j + 1] = w0 * ahi + w1 * bhi;
    }
    float4* out4 = (float4*)out;
    out4[2 * i]     = make_float4(o[0], o[1], o[2], o[3]);
    out4[2 * i + 1] = make_float4(o[4], o[5], o[6], o[7]);
}

extern "C" void kernel_launch(void* const* d_in, const int* in_sizes, int n_in,
                              void* d_out, int out_size, void* d_ws, size_t ws_size,
                              hipStream_t stream) {
    const float* x  = (const float*)d_in[0];   // [2,2048,1024]
    const float* gw = (const float*)d_in[1];   // [8,1024]
    const float* w1 = (const float*)d_in[2];   // [8,4096,1024]
    const float* w2 = (const float*)d_in[3];   // [8,1024,4096]
    float* out = (float*)d_out;

    char* ws = (char*)d_ws;
    unsigned short* w1b = (unsigned short*)(ws + W1B_OFF);
    unsigned short* w2b = (unsigned short*)(ws + W2B_OFF);
    unsigned short* xb  = (unsigned short*)(ws + XB_OFF);
    unsigned short* hb  = (unsigned short*)(ws + HB_OFF);
    unsigned short* ya  = (unsigned short*)(ws + YA_OFF);
    unsigned short* yb  = (unsigned short*)(ws + YB_OFF);   // aliases w1b (dead after gemm1)
    int*            meta = (int*)(ws + META_OFF);
    int* counts = meta + M_COUNTS;
    int* curs   = meta + M_CURS;
    int* texp   = meta + M_TEXP;
    int* tslot  = meta + M_TSLOT;
    int* stok   = meta + M_STOK;
    float* twf  = (float*)(meta + M_TWF);

    cvt_w_k<<<65536, 256, 0, stream>>>(w1, w2, w1b, w2b, NE * Idim * Hdim / 4, meta);
    router_k<<<T / 4, 256, 0, stream>>>(x, gw, out + OUT0, texp, twf, counts, xb);
    assign_k<<<32, 256, 0, stream>>>(texp, counts, curs, stok, tslot);
    gemm1_k<<<2304, 256, 0, stream>>>(xb, w1b, counts, stok, hb);
    gemm2_k<<<(Hdim / 128) * (SLOT_CAP / 128) * SPLITK, 256, 0, stream>>>(hb, w2b, counts, ya, yb);
    combine_k<<<T * Hdim / 8 / 256, 256, 0, stream>>>(ya, yb, tslot, twf, out);
}